// Round 13
// baseline (681.895 us; speedup 1.0000x reference)
//
#include <hip/hip_runtime.h>
#include <hip/hip_bf16.h>

// Problem constants (fixed by the reference)
#define B_ 1024
#define L_ 32
#define M_ 128
#define N_ 4096
#define S_ 32
#define ROWS (B_ * L_)          // 32768 rows of length N_

typedef __attribute__((ext_vector_type(8))) short    short8_t;   // 8 bf16 (4 VGPR)
typedef __attribute__((ext_vector_type(8))) unsigned short ushort8_t;
typedef __attribute__((ext_vector_type(4))) float    f32x4;

__device__ __forceinline__ unsigned short f2bf(float x) {  // RNE bf16
    unsigned u = __float_as_uint(x);
    unsigned r = (u + 0x7FFFu + ((u >> 16) & 1u)) >> 16;
    return (unsigned short)r;
}
__device__ __forceinline__ float bf2f(unsigned short h) {
    return __uint_as_float((unsigned)h << 16);
}

// ---------------------------------------------------------------------------
// K0: transpose W_d [L][M][N] -> W_dT [L][N][M] (runs AFTER encoder; WdT
// aliases the Wbf region)
// ---------------------------------------------------------------------------
__global__ __launch_bounds__(256) void transpose_wd(const float* __restrict__ Wd,
                                                    float* __restrict__ WdT) {
    __shared__ float t[32][33];
    int l = blockIdx.z;
    int n0 = blockIdx.x * 32, m0 = blockIdx.y * 32;
    int tx = threadIdx.x & 31, ty = threadIdx.x >> 5;
    const float* src = Wd + (size_t)l * M_ * N_;
    for (int i = ty; i < 32; i += 8)
        t[i][tx] = src[(size_t)(m0 + i) * N_ + n0 + tx];
    __syncthreads();
    float* dst = WdT + (size_t)l * N_ * M_;
    for (int i = ty; i < 32; i += 8)
        dst[(size_t)(n0 + i) * M_ + m0 + tx] = t[tx][i];
}

// ---------------------------------------------------------------------------
// P1: prep W (fused bias_dot): Wbf[l][n][128] = bf16(We row); cvec = b_d . We_n
// ---------------------------------------------------------------------------
__global__ __launch_bounds__(256) void prep_w(const float* __restrict__ We,
                                              const float* __restrict__ bd,
                                              unsigned short* __restrict__ Wbf,
                                              float* __restrict__ cvec) {
    int l = blockIdx.y;
    int tid = threadIdx.x;
    int nl = tid >> 4, t = tid & 15;
    int n = blockIdx.x * 16 + nl;
    const float* w = We + ((size_t)l * N_ + n) * M_ + t * 8;
    const float* b = bd + l * M_ + t * 8;
    float4 w0 = *(const float4*)(w), w1 = *(const float4*)(w + 4);
    float4 b0 = *(const float4*)(b), b1 = *(const float4*)(b + 4);
    ushort8_t o;
    o[0] = f2bf(w0.x); o[1] = f2bf(w0.y); o[2] = f2bf(w0.z); o[3] = f2bf(w0.w);
    o[4] = f2bf(w1.x); o[5] = f2bf(w1.y); o[6] = f2bf(w1.z); o[7] = f2bf(w1.w);
    *reinterpret_cast<ushort8_t*>(Wbf + ((size_t)l * N_ + n) * 128 + t * 8) = o;
    float s = w0.x*b0.x + w0.y*b0.y + w0.z*b0.z + w0.w*b0.w
            + w1.x*b1.x + w1.y*b1.y + w1.z*b1.z + w1.w*b1.w;
    #pragma unroll
    for (int oo = 8; oo > 0; oo >>= 1) s += __shfl_xor(s, oo, 64);
    if (t == 0) cvec[(size_t)l * N_ + n] = s;
}

// P2: prep A: Abf[l][b][128] = bf16(kin[b][l][:])
__global__ __launch_bounds__(256) void prep_a(const float* __restrict__ kin,
                                              unsigned short* __restrict__ Abf) {
    int g = blockIdx.x * 256 + threadIdx.x;       // over B*L*M
    int b = g >> 12, l = (g >> 7) & 31, m = g & 127;
    Abf[(((size_t)l * B_ + b) << 7) + m] = f2bf(kin[g]);
}

// ---------------------------------------------------------------------------
// K1: encoder approx GEMM via MFMA bf16, single term (K=128, 4 BK=32 steps).
// Epilogue: padded-LDS re-tile -> coalesced 16B stores to the HIGH half of
// each row's 16KB y slot.
// ---------------------------------------------------------------------------
__device__ __forceinline__ int swz(int row) { return (row & 3) ^ ((row >> 2) & 3); }

#define CP 136   // C-tile row pitch in shorts

__global__ __launch_bounds__(256) void encoder_mfma(const unsigned short* __restrict__ Abf,
                                                    const unsigned short* __restrict__ Wbf,
                                                    const float* __restrict__ cvec,
                                                    unsigned short* __restrict__ y16) {
    const int l   = blockIdx.z;
    const int bn0 = blockIdx.x * 128;
    const int bm0 = blockIdx.y * 128;
    __shared__ __align__(16) unsigned short smem[128 * CP];   // 34.8KB
    unsigned short* As = smem;
    unsigned short* Bs = smem + 128 * 32;
    const int tid  = threadIdx.x;
    const int lane = tid & 63, wave = tid >> 6;
    const int wr = wave >> 1, wc = wave & 1;

    const unsigned short* Ab = Abf + (((size_t)l * B_ + bm0) << 7);
    const unsigned short* Wb = Wbf + (((size_t)l * N_ + bn0) << 7);

    auto stage = [&](int k0) {
        #pragma unroll
        for (int i = 0; i < 2; ++i) {
            int p   = i * 256 + tid;
            int row = p >> 2;
            int lc  = (p & 3) ^ swz(row);
            const unsigned short* g = Ab + ((size_t)row << 7) + k0 + lc * 8;
            unsigned dst = (unsigned)((i * 256 + (tid & ~63)) * 16);
            __builtin_amdgcn_global_load_lds(
                (const __attribute__((address_space(1))) void*)g,
                (__attribute__((address_space(3))) void*)((char*)As + dst), 16, 0, 0);
        }
        #pragma unroll
        for (int i = 0; i < 2; ++i) {
            int p   = i * 256 + tid;
            int row = p >> 2;
            int lc  = (p & 3) ^ swz(row);
            const unsigned short* g = Wb + ((size_t)row << 7) + k0 + lc * 8;
            unsigned dst = (unsigned)((i * 256 + (tid & ~63)) * 16);
            __builtin_amdgcn_global_load_lds(
                (const __attribute__((address_space(1))) void*)g,
                (__attribute__((address_space(3))) void*)((char*)Bs + dst), 16, 0, 0);
        }
    };

    f32x4 acc[4][4];
    #pragma unroll
    for (int i = 0; i < 4; ++i)
        #pragma unroll
        for (int j = 0; j < 4; ++j) acc[i][j] = (f32x4){0.f, 0.f, 0.f, 0.f};

    stage(0);
    __syncthreads();

    #pragma unroll
    for (int t = 0; t < 4; ++t) {
        short8_t aF[4], bF[4];
        const int kg = lane >> 4;
        #pragma unroll
        for (int mt = 0; mt < 4; ++mt) {
            int row = wr * 64 + mt * 16 + (lane & 15);
            int pc  = kg ^ swz(row);
            aF[mt] = *reinterpret_cast<const short8_t*>(As + row * 32 + pc * 8);
        }
        #pragma unroll
        for (int nt = 0; nt < 4; ++nt) {
            int row = wc * 64 + nt * 16 + (lane & 15);
            int pc  = kg ^ swz(row);
            bF[nt] = *reinterpret_cast<const short8_t*>(Bs + row * 32 + pc * 8);
        }
        #pragma unroll
        for (int mt = 0; mt < 4; ++mt)
            #pragma unroll
            for (int nt = 0; nt < 4; ++nt)
                acc[mt][nt] = __builtin_amdgcn_mfma_f32_16x16x32_bf16(
                    aF[mt], bF[nt], acc[mt][nt], 0, 0, 0);

        if (t < 3) {
            __syncthreads();
            stage((t + 1) * 32);
            __syncthreads();
        }
    }

    __syncthreads();   // staging dead; repurpose LDS as C tile

    #pragma unroll
    for (int nt = 0; nt < 4; ++nt) {
        int nl = wc * 64 + nt * 16 + (lane & 15);
        float cj = cvec[(size_t)l * N_ + bn0 + nl];
        #pragma unroll
        for (int mt = 0; mt < 4; ++mt) {
            #pragma unroll
            for (int j = 0; j < 4; ++j) {
                int rl = wr * 64 + mt * 16 + (lane >> 4) * 4 + j;
                smem[rl * CP + nl] = f2bf(acc[mt][nt][j] - cj);
            }
        }
    }
    __syncthreads();

    #pragma unroll
    for (int i = 0; i < 8; ++i) {
        int chunk = i * 256 + tid;
        int r = chunk >> 4, cch = chunk & 15;
        ushort8_t v = *reinterpret_cast<const ushort8_t*>(smem + r * CP + cch * 8);
        unsigned short* dst = y16 + ((size_t)((bm0 + r) * L_ + l)) * 8192 + 4096 + bn0 + cch * 8;
        *reinterpret_cast<ushort8_t*>(dst) = v;
    }
}

// ---------------------------------------------------------------------------
// K2 (wave-per-row selector+decoder+WRITER, zero block barriers):
// shfl bisect (statistically seeded) on approx, pool via wave-local LDS
// atomics, float4-vectorized exact recompute (STRICT ascending-m fmaf order,
// bit-identical to r4), exact rank, then compose-write the ENTIRE 16KB y row
// (zeros + winners via LDS bitmask -- replaces zero_low/zero_high/scatter
// kernels; bytes hide under this kernel's latency phases); fused khat decode
// + residual. L-major wave order for L2 locality on We/WdT.
// ---------------------------------------------------------------------------
#define POOL 128
#define MARGIN 1.2e-3f

__global__ __launch_bounds__(256) void topk_decode(float* __restrict__ y,
                                                   const float* __restrict__ We,
                                                   const float* __restrict__ WdT,
                                                   const float* __restrict__ kin,
                                                   const float* __restrict__ cvec,
                                                   float* __restrict__ khat,
                                                   float* __restrict__ partial) {
    const int w    = threadIdx.x >> 6;          // wave id in block (0..3)
    const int lane = threadIdx.x & 63;
    const int wid  = (blockIdx.x << 2) + w;     // 0..32767, l-major
    const int l = wid >> 10, b = wid & 1023;
    const int row = b * L_ + l;

    __shared__ __align__(16) float kinS[4][M_];
    __shared__ int      pidxS[4][POOL];
    __shared__ float    pexS[4][POOL];
    __shared__ int      sidxS[4][S_];
    __shared__ float    svalS[4][S_];
    __shared__ unsigned maskS[4][128];          // 4096 bits: winner positions
    __shared__ int      pcntS[4];

    float* yo = y + (size_t)row * N_;
    const unsigned short* ya = (const unsigned short*)y + (size_t)row * 8192 + 4096;

    kinS[w][lane]      = kin[(size_t)row * M_ + lane];
    kinS[w][lane + 64] = kin[(size_t)row * M_ + lane + 64];
    maskS[w][lane & 127] = 0u;                  // lanes 0..63 cover words 0..63
    maskS[w][64 + lane]  = 0u;                  // and 64..127
    if (lane == 0) pcntS[w] = 0;

    // load 64 approx values (8 x 16B, coalesced)
    ushort8_t u[8];
    #pragma unroll
    for (int j = 0; j < 8; ++j)
        u[j] = *reinterpret_cast<const ushort8_t*>(ya + j * 512 + lane * 8);
    float a[64];
    #pragma unroll
    for (int j = 0; j < 8; ++j)
        #pragma unroll
        for (int e = 0; e < 8; ++e)
            a[j * 8 + e] = fabsf(bf2f(u[j][e]));

    // wave max + moments (for bisect seeding)
    float mx = 0.0f, s1 = 0.0f, s2 = 0.0f;
    #pragma unroll
    for (int i = 0; i < 64; ++i) {
        mx = fmaxf(mx, a[i]);
        s1 += a[i];
        s2 = fmaf(a[i], a[i], s2);
    }
    #pragma unroll
    for (int o = 32; o > 0; o >>= 1) {
        mx = fmaxf(mx, __shfl_xor(mx, o, 64));
        s1 += __shfl_xor(s1, o, 64);
        s2 += __shfl_xor(s2, o, 64);
    }
    const float mu  = s1 * (1.0f / 4096.0f);
    const float var = fmaxf(s2 * (1.0f / 4096.0f) - mu * mu, 0.0f);
    const float sg  = sqrtf(var);

    // bisect: invariant count(a >= lo) >= 32; tighten until count <= 48.
    // Iterations 0/1 use folded-normal quantile seeds (expected counts ~138,
    // ~40); wrong seeds only cost iterations (invariant update is unchanged).
    float lo = 0.0f, hi = mx;
    int cl = N_;
    for (int it = 0; it < 30 && cl > 48; ++it) {
        float t;
        if      (it == 0) t = mu + 2.20f * sg;
        else if (it == 1) t = mu + 2.96f * sg;
        else              t = 0.5f * (lo + hi);
        t = fminf(fmaxf(t, lo), hi);
        int c = 0;
        #pragma unroll
        for (int i = 0; i < 64; ++i) c += (a[i] >= t) ? 1 : 0;
        #pragma unroll
        for (int o = 32; o > 0; o >>= 1) c += __shfl_xor(c, o, 64);
        if (c >= S_) { lo = t; cl = c; } else { hi = t; }
    }

    // pool: approx >= lo - MARGIN (covers exact top-32; bound proven r9-r12)
    const float th = lo - MARGIN;
    #pragma unroll
    for (int j = 0; j < 8; ++j)
        #pragma unroll
        for (int e = 0; e < 8; ++e)
            if (a[j * 8 + e] >= th) {
                int p = atomicAdd(&pcntS[w], 1);
                if (p < POOL) pidxS[w][p] = j * 512 + lane * 8 + e;
            }
    __asm__ __volatile__("s_waitcnt lgkmcnt(0)" ::: "memory");
    int c = pcntS[w]; c = c < POOL ? c : POOL;

    // exact recompute: STRICT ascending-m fmaf chain (bit-identical to r4);
    // float4 loads (We global L2-hot, kin LDS) then 4 in-order scalar fmafs.
    if (lane < c) {
        int n = pidxS[w][lane];
        const float4* wp4 = reinterpret_cast<const float4*>(We + ((size_t)l * N_ + n) * M_);
        const float4* kp4 = reinterpret_cast<const float4*>(kinS[w]);
        float acc = -cvec[(size_t)l * N_ + n];
        #pragma unroll 8
        for (int m4 = 0; m4 < 32; ++m4) {
            float4 wv = wp4[m4], kv = kp4[m4];
            acc = fmaf(wv.x, kv.x, acc);
            acc = fmaf(wv.y, kv.y, acc);
            acc = fmaf(wv.z, kv.z, acc);
            acc = fmaf(wv.w, kv.w, acc);
        }
        pexS[w][lane] = acc;
    }
    if (lane + 64 < c) {
        int n = pidxS[w][lane + 64];
        const float4* wp4 = reinterpret_cast<const float4*>(We + ((size_t)l * N_ + n) * M_);
        const float4* kp4 = reinterpret_cast<const float4*>(kinS[w]);
        float acc = -cvec[(size_t)l * N_ + n];
        #pragma unroll 8
        for (int m4 = 0; m4 < 32; ++m4) {
            float4 wv = wp4[m4], kv = kp4[m4];
            acc = fmaf(wv.x, kv.x, acc);
            acc = fmaf(wv.y, kv.y, acc);
            acc = fmaf(wv.z, kv.z, acc);
            acc = fmaf(wv.w, kv.w, acc);
        }
        pexS[w][lane + 64] = acc;
    }
    __asm__ __volatile__("s_waitcnt lgkmcnt(0)" ::: "memory");

    // exact rank (lowest-index tie-break); winners into LDS lists
    for (int e = lane; e < c; e += 64) {
        float ae = fabsf(pexS[w][e]);
        int   ne = pidxS[w][e];
        int rank = 0;
        for (int j = 0; j < c; ++j) {
            float aj = fabsf(pexS[w][j]);
            rank += ((aj > ae) || (aj == ae && pidxS[w][j] < ne)) ? 1 : 0;
        }
        if (rank < S_) {
            sidxS[w][rank] = ne;
            svalS[w][rank] = pexS[w][e];
        }
    }
    __asm__ __volatile__("s_waitcnt lgkmcnt(0)" ::: "memory");

    // winner position bitmask
    if (lane < S_) {
        int n = sidxS[w][lane];
        atomicOr(&maskS[w][n >> 5], 1u << (n & 31));
    }
    __asm__ __volatile__("s_waitcnt lgkmcnt(0)" ::: "memory");

    // compose-write the ENTIRE y row: zeros with winners embedded.
    // 16 float4 slots per lane, coalesced (consecutive lanes -> 16B apart).
    // Safe vs the approx reads above: stores depend on rank -> a[] -> loads.
    #pragma unroll
    for (int i = 0; i < 16; ++i) {
        int slot = i * 64 + lane;               // float4 index 0..1023
        unsigned wm = maskS[w][slot >> 3];
        unsigned bits = (wm >> ((slot & 7) * 4)) & 0xFu;
        float4 v = {0.f, 0.f, 0.f, 0.f};
        if (bits) {
            #pragma unroll 4
            for (int j = 0; j < S_; ++j) {
                int n = sidxS[w][j];
                if ((n >> 2) == slot) reinterpret_cast<float*>(&v)[n & 3] = svalS[w][j];
            }
        }
        *reinterpret_cast<float4*>(yo + slot * 4) = v;
    }

    // fused decode: 2 dims per lane; WdT rows L2-resident (l-major)
    const float* wt = WdT + (size_t)l * N_ * M_;
    float acc0 = 0.0f, acc1 = 0.0f;
    #pragma unroll 4
    for (int j = 0; j < S_; ++j) {
        float v = svalS[w][j];
        const float* wrp = wt + (size_t)sidxS[w][j] * M_;
        acc0 = fmaf(v, wrp[lane], acc0);
        acc1 = fmaf(v, wrp[lane + 64], acc1);
    }
    khat[(size_t)row * M_ + lane]      = acc0;
    khat[(size_t)row * M_ + lane + 64] = acc1;
    float r0 = acc0 - kinS[w][lane];
    float r1 = acc1 - kinS[w][lane + 64];
    float s = r0 * r0 + r1 * r1;
    #pragma unroll
    for (int o = 32; o > 0; o >>= 1) s += __shfl_xor(s, o, 64);
    if (lane == 0) partial[row] = s;
}

// ---------------------------------------------------------------------------
// K4: deterministic reduction of 32768 partials -> loss (float4 loads)
// ---------------------------------------------------------------------------
__global__ __launch_bounds__(256) void reduce_loss(const float* __restrict__ partial,
                                                   float* __restrict__ out_loss) {
    __shared__ float red[256];
    int tid = threadIdx.x;
    float s = 0.0f;
    for (int i = tid; i < ROWS / 4; i += 256) {
        float4 v = reinterpret_cast<const float4*>(partial)[i];
        s += v.x + v.y + v.z + v.w;
    }
    red[tid] = s;
    __syncthreads();
    for (int off = 128; off > 0; off >>= 1) {
        if (tid < off) red[tid] += red[tid + off];
        __syncthreads();
    }
    if (tid == 0) out_loss[0] = red[0] / (float)((size_t)B_ * L_ * M_);
}

// ---------------------------------------------------------------------------
extern "C" void kernel_launch(void* const* d_in, const int* in_sizes, int n_in,
                              void* d_out, int out_size, void* d_ws, size_t ws_size,
                              hipStream_t stream) {
    const float* kin = (const float*)d_in[0];   // [B][L][M]
    const float* We  = (const float*)d_in[1];   // [L][N][M]
    // d_in[2] = b_e (unused by reference encode())
    const float* Wd  = (const float*)d_in[3];   // [L][M][N]
    const float* bd  = (const float*)d_in[4];   // [L][M]
    // d_in[5] = s (==32, hardcoded)

    float* out   = (float*)d_out;
    float* loss  = out;                                   // [1]
    float* khat  = out + 1;                               // [B*L*M]
    float* y_out = out + 1 + (size_t)B_ * L_ * M_;        // [B*L*N]

    // workspace layout (region0 shared: Wbf during encode, WdT after)
    char* ws = (char*)d_ws;
    unsigned short* Wbf = (unsigned short*)ws;                   // 32 MiB (in 64 MiB region0)
    float*          WdT = (float*)ws;                            // 64 MiB (aliases Wbf)
    unsigned short* Abf = (unsigned short*)(ws + (64u << 20));   // 8 MiB
    float* cvec    = (float*)(ws + (80u << 20));                 // 512 KiB
    float* partial = (float*)(ws + (81u << 20));                 // 128 KiB

    prep_w<<<dim3(N_ / 16, L_), 256, 0, stream>>>(We, bd, Wbf, cvec);
    prep_a<<<(B_ * L_ * M_) / 256, 256, 0, stream>>>(kin, Abf);
    encoder_mfma<<<dim3(N_ / 128, B_ / 128, L_), 256, 0, stream>>>(
        Abf, Wbf, cvec, (unsigned short*)y_out);
    // Wbf dead now; transpose overwrites region0 with WdT
    transpose_wd<<<dim3(N_ / 32, M_ / 32, L_), 256, 0, stream>>>(Wd, WdT);
    // wave-per-row selector + decoder + full-row y writer
    topk_decode<<<ROWS / 4, 256, 0, stream>>>(y_out, We, WdT, kin, cvec,
                                              khat, partial);
    reduce_loss<<<1, 256, 0, stream>>>(partial, loss);
}

// Round 14
// 614.829 us; speedup vs baseline: 1.1091x; 1.1091x over previous
//
#include <hip/hip_runtime.h>
#include <hip/hip_bf16.h>

// Problem constants (fixed by the reference)
#define B_ 1024
#define L_ 32
#define M_ 128
#define N_ 4096
#define S_ 32
#define ROWS (B_ * L_)          // 32768 rows of length N_

typedef __attribute__((ext_vector_type(8))) short    short8_t;   // 8 bf16 (4 VGPR)
typedef __attribute__((ext_vector_type(8))) unsigned short ushort8_t;
typedef __attribute__((ext_vector_type(4))) float    f32x4;

__device__ __forceinline__ unsigned short f2bf(float x) {  // RNE bf16
    unsigned u = __float_as_uint(x);
    unsigned r = (u + 0x7FFFu + ((u >> 16) & 1u)) >> 16;
    return (unsigned short)r;
}
__device__ __forceinline__ float bf2f(unsigned short h) {
    return __uint_as_float((unsigned)h << 16);
}

// ---------------------------------------------------------------------------
// K0: transpose W_d [L][M][N] -> W_dT [L][N][M] (runs AFTER encoder; WdT
// aliases the Wbf region)
// ---------------------------------------------------------------------------
__global__ __launch_bounds__(256) void transpose_wd(const float* __restrict__ Wd,
                                                    float* __restrict__ WdT) {
    __shared__ float t[32][33];
    int l = blockIdx.z;
    int n0 = blockIdx.x * 32, m0 = blockIdx.y * 32;
    int tx = threadIdx.x & 31, ty = threadIdx.x >> 5;
    const float* src = Wd + (size_t)l * M_ * N_;
    for (int i = ty; i < 32; i += 8)
        t[i][tx] = src[(size_t)(m0 + i) * N_ + n0 + tx];
    __syncthreads();
    float* dst = WdT + (size_t)l * N_ * M_;
    for (int i = ty; i < 32; i += 8)
        dst[(size_t)(n0 + i) * M_ + m0 + tx] = t[tx][i];
}

// ---------------------------------------------------------------------------
// Z1: zero the LOW 8KB half of every y row slot (pure streaming, full BW).
// Runs FIRST; the encoder writes approx into the HIGH half only, and
// topk_decode scatters low-half winners directly onto these zeros.
// ---------------------------------------------------------------------------
__global__ __launch_bounds__(256) void zero_y_low(float* __restrict__ y) {
    const float4 z = {0.f, 0.f, 0.f, 0.f};
    int idx = blockIdx.x * 256 + threadIdx.x;
    for (int i = idx; i < ROWS * 512; i += 2048 * 256) {
        int row = i >> 9, slot = i & 511;
        reinterpret_cast<float4*>(y + (size_t)row * N_)[slot] = z;
    }
}

// Z2: zero the HIGH 8KB half (overwrites the approx). Pure streaming.
__global__ __launch_bounds__(256) void zero_y_high(float* __restrict__ y) {
    const float4 z = {0.f, 0.f, 0.f, 0.f};
    int idx = blockIdx.x * 256 + threadIdx.x;
    for (int i = idx; i < ROWS * 512; i += 2048 * 256) {
        int row = i >> 9, slot = i & 511;
        reinterpret_cast<float4*>(y + (size_t)row * N_ + 2048)[slot] = z;
    }
}

// Z3: scatter high-half winners (n >= 2048) after zero_y_high. Tiny.
__global__ __launch_bounds__(256) void scatter_high(float* __restrict__ y,
                                                    const int* __restrict__ cidx,
                                                    const float* __restrict__ cval) {
    int g = blockIdx.x * 256 + threadIdx.x;       // over ROWS*S
    int row = g >> 5;
    int n = cidx[g];
    if (n >= 2048) y[(size_t)row * N_ + n] = cval[g];
}

// ---------------------------------------------------------------------------
// P1: prep W (fused bias_dot): Wbf[l][n][128] = bf16(We row); cvec = b_d . We_n
// ---------------------------------------------------------------------------
__global__ __launch_bounds__(256) void prep_w(const float* __restrict__ We,
                                              const float* __restrict__ bd,
                                              unsigned short* __restrict__ Wbf,
                                              float* __restrict__ cvec) {
    int l = blockIdx.y;
    int tid = threadIdx.x;
    int nl = tid >> 4, t = tid & 15;
    int n = blockIdx.x * 16 + nl;
    const float* w = We + ((size_t)l * N_ + n) * M_ + t * 8;
    const float* b = bd + l * M_ + t * 8;
    float4 w0 = *(const float4*)(w), w1 = *(const float4*)(w + 4);
    float4 b0 = *(const float4*)(b), b1 = *(const float4*)(b + 4);
    ushort8_t o;
    o[0] = f2bf(w0.x); o[1] = f2bf(w0.y); o[2] = f2bf(w0.z); o[3] = f2bf(w0.w);
    o[4] = f2bf(w1.x); o[5] = f2bf(w1.y); o[6] = f2bf(w1.z); o[7] = f2bf(w1.w);
    *reinterpret_cast<ushort8_t*>(Wbf + ((size_t)l * N_ + n) * 128 + t * 8) = o;
    float s = w0.x*b0.x + w0.y*b0.y + w0.z*b0.z + w0.w*b0.w
            + w1.x*b1.x + w1.y*b1.y + w1.z*b1.z + w1.w*b1.w;
    #pragma unroll
    for (int oo = 8; oo > 0; oo >>= 1) s += __shfl_xor(s, oo, 64);
    if (t == 0) cvec[(size_t)l * N_ + n] = s;
}

// P2: prep A: Abf[l][b][128] = bf16(kin[b][l][:])
__global__ __launch_bounds__(256) void prep_a(const float* __restrict__ kin,
                                              unsigned short* __restrict__ Abf) {
    int g = blockIdx.x * 256 + threadIdx.x;       // over B*L*M
    int b = g >> 12, l = (g >> 7) & 31, m = g & 127;
    Abf[(((size_t)l * B_ + b) << 7) + m] = f2bf(kin[g]);
}

// ---------------------------------------------------------------------------
// K1: encoder approx GEMM via MFMA bf16, single term (K=128, 4 BK=32 steps).
// Epilogue: padded-LDS re-tile -> coalesced 16B stores to the HIGH half.
// ---------------------------------------------------------------------------
__device__ __forceinline__ int swz(int row) { return (row & 3) ^ ((row >> 2) & 3); }

#define CP 136   // C-tile row pitch in shorts

__global__ __launch_bounds__(256) void encoder_mfma(const unsigned short* __restrict__ Abf,
                                                    const unsigned short* __restrict__ Wbf,
                                                    const float* __restrict__ cvec,
                                                    unsigned short* __restrict__ y16) {
    const int l   = blockIdx.z;
    const int bn0 = blockIdx.x * 128;
    const int bm0 = blockIdx.y * 128;
    __shared__ __align__(16) unsigned short smem[128 * CP];   // 34.8KB
    unsigned short* As = smem;
    unsigned short* Bs = smem + 128 * 32;
    const int tid  = threadIdx.x;
    const int lane = tid & 63, wave = tid >> 6;
    const int wr = wave >> 1, wc = wave & 1;

    const unsigned short* Ab = Abf + (((size_t)l * B_ + bm0) << 7);
    const unsigned short* Wb = Wbf + (((size_t)l * N_ + bn0) << 7);

    auto stage = [&](int k0) {
        #pragma unroll
        for (int i = 0; i < 2; ++i) {
            int p   = i * 256 + tid;
            int row = p >> 2;
            int lc  = (p & 3) ^ swz(row);
            const unsigned short* g = Ab + ((size_t)row << 7) + k0 + lc * 8;
            unsigned dst = (unsigned)((i * 256 + (tid & ~63)) * 16);
            __builtin_amdgcn_global_load_lds(
                (const __attribute__((address_space(1))) void*)g,
                (__attribute__((address_space(3))) void*)((char*)As + dst), 16, 0, 0);
        }
        #pragma unroll
        for (int i = 0; i < 2; ++i) {
            int p   = i * 256 + tid;
            int row = p >> 2;
            int lc  = (p & 3) ^ swz(row);
            const unsigned short* g = Wb + ((size_t)row << 7) + k0 + lc * 8;
            unsigned dst = (unsigned)((i * 256 + (tid & ~63)) * 16);
            __builtin_amdgcn_global_load_lds(
                (const __attribute__((address_space(1))) void*)g,
                (__attribute__((address_space(3))) void*)((char*)Bs + dst), 16, 0, 0);
        }
    };

    f32x4 acc[4][4];
    #pragma unroll
    for (int i = 0; i < 4; ++i)
        #pragma unroll
        for (int j = 0; j < 4; ++j) acc[i][j] = (f32x4){0.f, 0.f, 0.f, 0.f};

    stage(0);
    __syncthreads();

    #pragma unroll
    for (int t = 0; t < 4; ++t) {
        short8_t aF[4], bF[4];
        const int kg = lane >> 4;
        #pragma unroll
        for (int mt = 0; mt < 4; ++mt) {
            int row = wr * 64 + mt * 16 + (lane & 15);
            int pc  = kg ^ swz(row);
            aF[mt] = *reinterpret_cast<const short8_t*>(As + row * 32 + pc * 8);
        }
        #pragma unroll
        for (int nt = 0; nt < 4; ++nt) {
            int row = wc * 64 + nt * 16 + (lane & 15);
            int pc  = kg ^ swz(row);
            bF[nt] = *reinterpret_cast<const short8_t*>(Bs + row * 32 + pc * 8);
        }
        #pragma unroll
        for (int mt = 0; mt < 4; ++mt)
            #pragma unroll
            for (int nt = 0; nt < 4; ++nt)
                acc[mt][nt] = __builtin_amdgcn_mfma_f32_16x16x32_bf16(
                    aF[mt], bF[nt], acc[mt][nt], 0, 0, 0);

        if (t < 3) {
            __syncthreads();
            stage((t + 1) * 32);
            __syncthreads();
        }
    }

    __syncthreads();   // staging dead; repurpose LDS as C tile

    #pragma unroll
    for (int nt = 0; nt < 4; ++nt) {
        int nl = wc * 64 + nt * 16 + (lane & 15);
        float cj = cvec[(size_t)l * N_ + bn0 + nl];
        #pragma unroll
        for (int mt = 0; mt < 4; ++mt) {
            #pragma unroll
            for (int j = 0; j < 4; ++j) {
                int rl = wr * 64 + mt * 16 + (lane >> 4) * 4 + j;
                smem[rl * CP + nl] = f2bf(acc[mt][nt][j] - cj);
            }
        }
    }
    __syncthreads();

    #pragma unroll
    for (int i = 0; i < 8; ++i) {
        int chunk = i * 256 + tid;
        int r = chunk >> 4, cch = chunk & 15;
        ushort8_t v = *reinterpret_cast<const ushort8_t*>(smem + r * CP + cch * 8);
        unsigned short* dst = y16 + ((size_t)((bm0 + r) * L_ + l)) * 8192 + 4096 + bn0 + cch * 8;
        *reinterpret_cast<ushort8_t*>(dst) = v;
    }
}

// ---------------------------------------------------------------------------
// K2 (wave-per-row selector+decoder, zero block barriers) == round 12 +
// statistically-seeded bisect (folded-normal quantiles; invariant update
// unchanged so wrong seeds only cost iterations, never correctness).
// ---------------------------------------------------------------------------
#define POOL 96
#define MARGIN 1.2e-3f

__global__ __launch_bounds__(256) void topk_decode(float* __restrict__ y,
                                                   const float* __restrict__ We,
                                                   const float* __restrict__ WdT,
                                                   const float* __restrict__ kin,
                                                   const float* __restrict__ cvec,
                                                   int* __restrict__ cidx,
                                                   float* __restrict__ cval,
                                                   float* __restrict__ khat,
                                                   float* __restrict__ partial) {
    const int w    = threadIdx.x >> 6;          // wave id in block (0..3)
    const int lane = threadIdx.x & 63;
    const int wid  = (blockIdx.x << 2) + w;     // 0..32767, l-major
    const int l = wid >> 10, b = wid & 1023;
    const int row = b * L_ + l;

    __shared__ __align__(16) float kinS[4][M_];
    __shared__ int   pidxS[4][POOL];
    __shared__ float pexS[4][POOL];
    __shared__ int   sidxS[4][S_];
    __shared__ float svalS[4][S_];
    __shared__ int   pcntS[4];

    float* yo = y + (size_t)row * N_;
    const unsigned short* ya = (const unsigned short*)y + (size_t)row * 8192 + 4096;

    kinS[w][lane]      = kin[(size_t)row * M_ + lane];
    kinS[w][lane + 64] = kin[(size_t)row * M_ + lane + 64];
    if (lane == 0) pcntS[w] = 0;

    // load 64 approx values (8 x 16B, coalesced)
    ushort8_t u[8];
    #pragma unroll
    for (int j = 0; j < 8; ++j)
        u[j] = *reinterpret_cast<const ushort8_t*>(ya + j * 512 + lane * 8);
    float a[64];
    #pragma unroll
    for (int j = 0; j < 8; ++j)
        #pragma unroll
        for (int e = 0; e < 8; ++e)
            a[j * 8 + e] = fabsf(bf2f(u[j][e]));

    // wave max + moments (for bisect seeding)
    float mx = 0.0f, s1 = 0.0f, s2 = 0.0f;
    #pragma unroll
    for (int i = 0; i < 64; ++i) {
        mx = fmaxf(mx, a[i]);
        s1 += a[i];
        s2 = fmaf(a[i], a[i], s2);
    }
    #pragma unroll
    for (int o = 32; o > 0; o >>= 1) {
        mx = fmaxf(mx, __shfl_xor(mx, o, 64));
        s1 += __shfl_xor(s1, o, 64);
        s2 += __shfl_xor(s2, o, 64);
    }
    const float mu  = s1 * (1.0f / 4096.0f);
    const float var = fmaxf(s2 * (1.0f / 4096.0f) - mu * mu, 0.0f);
    const float sg  = sqrtf(var);

    // bisect: invariant count(a >= lo) >= 32; tighten until count <= 40.
    // Iters 0/1 use folded-normal quantile seeds (expected counts ~139, ~40);
    // ~80% of rows terminate after 2 counting rounds.
    float lo = 0.0f, hi = mx;
    int cl = N_;
    for (int it = 0; it < 30 && cl > 40; ++it) {
        float t;
        if      (it == 0) t = mu + 2.20f * sg;
        else if (it == 1) t = mu + 2.96f * sg;
        else              t = 0.5f * (lo + hi);
        t = fminf(fmaxf(t, lo), hi);
        int c = 0;
        #pragma unroll
        for (int i = 0; i < 64; ++i) c += (a[i] >= t) ? 1 : 0;
        #pragma unroll
        for (int o = 32; o > 0; o >>= 1) c += __shfl_xor(c, o, 64);
        if (c >= S_) { lo = t; cl = c; } else { hi = t; }
    }

    // pool: approx >= lo - MARGIN (covers exact top-32; bound proven r9-r12)
    const float th = lo - MARGIN;
    #pragma unroll
    for (int j = 0; j < 8; ++j)
        #pragma unroll
        for (int e = 0; e < 8; ++e)
            if (a[j * 8 + e] >= th) {
                int p = atomicAdd(&pcntS[w], 1);
                if (p < POOL) pidxS[w][p] = j * 512 + lane * 8 + e;
            }
    __asm__ __volatile__("s_waitcnt lgkmcnt(0)" ::: "memory");
    int c = pcntS[w]; c = c < POOL ? c : POOL;

    // exact recompute: STRICT ascending-m fmaf chain (bit-identical to r4);
    // float4 loads (We global L2-hot, kin LDS) then 4 in-order scalar fmafs.
    if (lane < c) {
        int n = pidxS[w][lane];
        const float4* wp4 = reinterpret_cast<const float4*>(We + ((size_t)l * N_ + n) * M_);
        const float4* kp4 = reinterpret_cast<const float4*>(kinS[w]);
        float acc = -cvec[(size_t)l * N_ + n];
        #pragma unroll 8
        for (int m4 = 0; m4 < 32; ++m4) {
            float4 wv = wp4[m4], kv = kp4[m4];
            acc = fmaf(wv.x, kv.x, acc);
            acc = fmaf(wv.y, kv.y, acc);
            acc = fmaf(wv.z, kv.z, acc);
            acc = fmaf(wv.w, kv.w, acc);
        }
        pexS[w][lane] = acc;
    }
    if (lane + 64 < c) {
        int n = pidxS[w][lane + 64];
        const float4* wp4 = reinterpret_cast<const float4*>(We + ((size_t)l * N_ + n) * M_);
        const float4* kp4 = reinterpret_cast<const float4*>(kinS[w]);
        float acc = -cvec[(size_t)l * N_ + n];
        #pragma unroll 8
        for (int m4 = 0; m4 < 32; ++m4) {
            float4 wv = wp4[m4], kv = kp4[m4];
            acc = fmaf(wv.x, kv.x, acc);
            acc = fmaf(wv.y, kv.y, acc);
            acc = fmaf(wv.z, kv.z, acc);
            acc = fmaf(wv.w, kv.w, acc);
        }
        pexS[w][lane + 64] = acc;
    }
    __asm__ __volatile__("s_waitcnt lgkmcnt(0)" ::: "memory");

    // exact rank (lowest-index tie-break); winners into LDS lists
    for (int e = lane; e < c; e += 64) {
        float ae = fabsf(pexS[w][e]);
        int   ne = pidxS[w][e];
        int rank = 0;
        for (int j = 0; j < c; ++j) {
            float aj = fabsf(pexS[w][j]);
            rank += ((aj > ae) || (aj == ae && pidxS[w][j] < ne)) ? 1 : 0;
        }
        if (rank < S_) {
            sidxS[w][rank] = ne;
            svalS[w][rank] = pexS[w][e];
        }
    }
    __asm__ __volatile__("s_waitcnt lgkmcnt(0)" ::: "memory");

    // emit winner lists; DIRECT scatter of low-half winners (that region was
    // zeroed by zero_y_low before the encoder and has no other writer)
    if (lane < S_) {
        int n = sidxS[w][lane];
        float v = svalS[w][lane];
        cidx[(size_t)row * S_ + lane] = n;
        cval[(size_t)row * S_ + lane] = v;
        if (n < 2048) yo[n] = v;
    }

    // fused decode: 2 dims per lane; WdT rows L2-resident (l-major)
    const float* wt = WdT + (size_t)l * N_ * M_;
    float acc0 = 0.0f, acc1 = 0.0f;
    #pragma unroll 4
    for (int j = 0; j < S_; ++j) {
        float v = svalS[w][j];
        const float* wrp = wt + (size_t)sidxS[w][j] * M_;
        acc0 = fmaf(v, wrp[lane], acc0);
        acc1 = fmaf(v, wrp[lane + 64], acc1);
    }
    khat[(size_t)row * M_ + lane]      = acc0;
    khat[(size_t)row * M_ + lane + 64] = acc1;
    float r0 = acc0 - kinS[w][lane];
    float r1 = acc1 - kinS[w][lane + 64];
    float s = r0 * r0 + r1 * r1;
    #pragma unroll
    for (int o = 32; o > 0; o >>= 1) s += __shfl_xor(s, o, 64);
    if (lane == 0) partial[row] = s;
}

// ---------------------------------------------------------------------------
// K4: deterministic reduction of 32768 partials -> loss (float4 loads)
// ---------------------------------------------------------------------------
__global__ __launch_bounds__(256) void reduce_loss(const float* __restrict__ partial,
                                                   float* __restrict__ out_loss) {
    __shared__ float red[256];
    int tid = threadIdx.x;
    float s = 0.0f;
    for (int i = tid; i < ROWS / 4; i += 256) {
        float4 v = reinterpret_cast<const float4*>(partial)[i];
        s += v.x + v.y + v.z + v.w;
    }
    red[tid] = s;
    __syncthreads();
    for (int off = 128; off > 0; off >>= 1) {
        if (tid < off) red[tid] += red[tid + off];
        __syncthreads();
    }
    if (tid == 0) out_loss[0] = red[0] / (float)((size_t)B_ * L_ * M_);
}

// ---------------------------------------------------------------------------
extern "C" void kernel_launch(void* const* d_in, const int* in_sizes, int n_in,
                              void* d_out, int out_size, void* d_ws, size_t ws_size,
                              hipStream_t stream) {
    const float* kin = (const float*)d_in[0];   // [B][L][M]
    const float* We  = (const float*)d_in[1];   // [L][N][M]
    // d_in[2] = b_e (unused by reference encode())
    const float* Wd  = (const float*)d_in[3];   // [L][M][N]
    const float* bd  = (const float*)d_in[4];   // [L][M]
    // d_in[5] = s (==32, hardcoded)

    float* out   = (float*)d_out;
    float* loss  = out;                                   // [1]
    float* khat  = out + 1;                               // [B*L*M]
    float* y_out = out + 1 + (size_t)B_ * L_ * M_;        // [B*L*N]

    // workspace layout (region0 shared: Wbf during encode, WdT after)
    char* ws = (char*)d_ws;
    unsigned short* Wbf = (unsigned short*)ws;                   // 32 MiB (in 64 MiB region0)
    float*          WdT = (float*)ws;                            // 64 MiB (aliases Wbf)
    unsigned short* Abf = (unsigned short*)(ws + (64u << 20));   // 8 MiB
    int*   cidx    = (int*)  (ws + (72u << 20));                 // 4 MiB
    float* cval    = (float*)(ws + (76u << 20));                 // 4 MiB
    float* cvec    = (float*)(ws + (80u << 20));                 // 512 KiB
    float* partial = (float*)(ws + (81u << 20));                 // 128 KiB

    // zero low halves of y first (approx lives in high halves)
    zero_y_low<<<2048, 256, 0, stream>>>(y_out);
    prep_w<<<dim3(N_ / 16, L_), 256, 0, stream>>>(We, bd, Wbf, cvec);
    prep_a<<<(B_ * L_ * M_) / 256, 256, 0, stream>>>(kin, Abf);
    encoder_mfma<<<dim3(N_ / 128, B_ / 128, L_), 256, 0, stream>>>(
        Abf, Wbf, cvec, (unsigned short*)y_out);
    // Wbf dead now; transpose overwrites region0 with WdT
    transpose_wd<<<dim3(N_ / 32, M_ / 32, L_), 256, 0, stream>>>(Wd, WdT);
    // wave-per-row selector + decoder (direct low-half scatter)
    topk_decode<<<ROWS / 4, 256, 0, stream>>>(y_out, We, WdT, kin, cvec,
                                              cidx, cval, khat, partial);
    // streaming finishers: zero high halves, then scatter high winners
    zero_y_high<<<2048, 256, 0, stream>>>(y_out);
    scatter_high<<<(ROWS * S_) / 256, 256, 0, stream>>>(y_out, cidx, cval);
    reduce_loss<<<1, 256, 0, stream>>>(partial, loss);
}

// Round 15
// 584.313 us; speedup vs baseline: 1.1670x; 1.0522x over previous
//
#include <hip/hip_runtime.h>
#include <hip/hip_bf16.h>

// Problem constants (fixed by the reference)
#define B_ 1024
#define L_ 32
#define M_ 128
#define N_ 4096
#define S_ 32
#define ROWS (B_ * L_)          // 32768 rows of length N_

typedef __attribute__((ext_vector_type(8))) short    short8_t;   // 8 bf16 (4 VGPR)
typedef __attribute__((ext_vector_type(8))) unsigned short ushort8_t;
typedef __attribute__((ext_vector_type(4))) float    f32x4;

__device__ __forceinline__ unsigned short f2bf(float x) {  // RNE bf16
    unsigned u = __float_as_uint(x);
    unsigned r = (u + 0x7FFFu + ((u >> 16) & 1u)) >> 16;
    return (unsigned short)r;
}
__device__ __forceinline__ float bf2f(unsigned short h) {
    return __uint_as_float((unsigned)h << 16);
}

// ---------------------------------------------------------------------------
// K0: transpose W_d [L][M][N] -> W_dT [L][N][M] (runs AFTER encoder; WdT
// aliases the Wbf region)
// ---------------------------------------------------------------------------
__global__ __launch_bounds__(256) void transpose_wd(const float* __restrict__ Wd,
                                                    float* __restrict__ WdT) {
    __shared__ float t[32][33];
    int l = blockIdx.z;
    int n0 = blockIdx.x * 32, m0 = blockIdx.y * 32;
    int tx = threadIdx.x & 31, ty = threadIdx.x >> 5;
    const float* src = Wd + (size_t)l * M_ * N_;
    for (int i = ty; i < 32; i += 8)
        t[i][tx] = src[(size_t)(m0 + i) * N_ + n0 + tx];
    __syncthreads();
    float* dst = WdT + (size_t)l * N_ * M_;
    for (int i = ty; i < 32; i += 8)
        dst[(size_t)(n0 + i) * M_ + m0 + tx] = t[tx][i];
}

// ---------------------------------------------------------------------------
// Z1: zero the LOW 8KB half of every y row slot (pure streaming, full BW).
// ---------------------------------------------------------------------------
__global__ __launch_bounds__(256) void zero_y_low(float* __restrict__ y) {
    const float4 z = {0.f, 0.f, 0.f, 0.f};
    int idx = blockIdx.x * 256 + threadIdx.x;
    for (int i = idx; i < ROWS * 512; i += 2048 * 256) {
        int row = i >> 9, slot = i & 511;
        reinterpret_cast<float4*>(y + (size_t)row * N_)[slot] = z;
    }
}

// Z2: zero the HIGH 8KB half (overwrites the approx). Pure streaming.
__global__ __launch_bounds__(256) void zero_y_high(float* __restrict__ y) {
    const float4 z = {0.f, 0.f, 0.f, 0.f};
    int idx = blockIdx.x * 256 + threadIdx.x;
    for (int i = idx; i < ROWS * 512; i += 2048 * 256) {
        int row = i >> 9, slot = i & 511;
        reinterpret_cast<float4*>(y + (size_t)row * N_ + 2048)[slot] = z;
    }
}

// Z3: scatter high-half winners (n >= 2048) after zero_y_high. Tiny.
__global__ __launch_bounds__(256) void scatter_high(float* __restrict__ y,
                                                    const int* __restrict__ cidx,
                                                    const float* __restrict__ cval) {
    int g = blockIdx.x * 256 + threadIdx.x;       // over ROWS*S
    int row = g >> 5;
    int n = cidx[g];
    if (n >= 2048) y[(size_t)row * N_ + n] = cval[g];
}

// ---------------------------------------------------------------------------
// P1: prep W (fused bias_dot): Wbf[l][n][128] = bf16(We row); cvec = b_d . We_n
// ---------------------------------------------------------------------------
__global__ __launch_bounds__(256) void prep_w(const float* __restrict__ We,
                                              const float* __restrict__ bd,
                                              unsigned short* __restrict__ Wbf,
                                              float* __restrict__ cvec) {
    int l = blockIdx.y;
    int tid = threadIdx.x;
    int nl = tid >> 4, t = tid & 15;
    int n = blockIdx.x * 16 + nl;
    const float* w = We + ((size_t)l * N_ + n) * M_ + t * 8;
    const float* b = bd + l * M_ + t * 8;
    float4 w0 = *(const float4*)(w), w1 = *(const float4*)(w + 4);
    float4 b0 = *(const float4*)(b), b1 = *(const float4*)(b + 4);
    ushort8_t o;
    o[0] = f2bf(w0.x); o[1] = f2bf(w0.y); o[2] = f2bf(w0.z); o[3] = f2bf(w0.w);
    o[4] = f2bf(w1.x); o[5] = f2bf(w1.y); o[6] = f2bf(w1.z); o[7] = f2bf(w1.w);
    *reinterpret_cast<ushort8_t*>(Wbf + ((size_t)l * N_ + n) * 128 + t * 8) = o;
    float s = w0.x*b0.x + w0.y*b0.y + w0.z*b0.z + w0.w*b0.w
            + w1.x*b1.x + w1.y*b1.y + w1.z*b1.z + w1.w*b1.w;
    #pragma unroll
    for (int oo = 8; oo > 0; oo >>= 1) s += __shfl_xor(s, oo, 64);
    if (t == 0) cvec[(size_t)l * N_ + n] = s;
}

// P2: prep A: Abf[l][b][128] = bf16(kin[b][l][:])
__global__ __launch_bounds__(256) void prep_a(const float* __restrict__ kin,
                                              unsigned short* __restrict__ Abf) {
    int g = blockIdx.x * 256 + threadIdx.x;       // over B*L*M
    int b = g >> 12, l = (g >> 7) & 31, m = g & 127;
    Abf[(((size_t)l * B_ + b) << 7) + m] = f2bf(kin[g]);
}

// ---------------------------------------------------------------------------
// K1: encoder approx GEMM via MFMA bf16, single term (K=128, 4 BK=32 steps).
// Epilogue: padded-LDS re-tile -> coalesced 16B stores to the HIGH half.
// ---------------------------------------------------------------------------
__device__ __forceinline__ int swz(int row) { return (row & 3) ^ ((row >> 2) & 3); }

#define CP 136   // C-tile row pitch in shorts

__global__ __launch_bounds__(256) void encoder_mfma(const unsigned short* __restrict__ Abf,
                                                    const unsigned short* __restrict__ Wbf,
                                                    const float* __restrict__ cvec,
                                                    unsigned short* __restrict__ y16) {
    const int l   = blockIdx.z;
    const int bn0 = blockIdx.x * 128;
    const int bm0 = blockIdx.y * 128;
    __shared__ __align__(16) unsigned short smem[128 * CP];   // 34.8KB
    unsigned short* As = smem;
    unsigned short* Bs = smem + 128 * 32;
    const int tid  = threadIdx.x;
    const int lane = tid & 63, wave = tid >> 6;
    const int wr = wave >> 1, wc = wave & 1;

    const unsigned short* Ab = Abf + (((size_t)l * B_ + bm0) << 7);
    const unsigned short* Wb = Wbf + (((size_t)l * N_ + bn0) << 7);

    auto stage = [&](int k0) {
        #pragma unroll
        for (int i = 0; i < 2; ++i) {
            int p   = i * 256 + tid;
            int row = p >> 2;
            int lc  = (p & 3) ^ swz(row);
            const unsigned short* g = Ab + ((size_t)row << 7) + k0 + lc * 8;
            unsigned dst = (unsigned)((i * 256 + (tid & ~63)) * 16);
            __builtin_amdgcn_global_load_lds(
                (const __attribute__((address_space(1))) void*)g,
                (__attribute__((address_space(3))) void*)((char*)As + dst), 16, 0, 0);
        }
        #pragma unroll
        for (int i = 0; i < 2; ++i) {
            int p   = i * 256 + tid;
            int row = p >> 2;
            int lc  = (p & 3) ^ swz(row);
            const unsigned short* g = Wb + ((size_t)row << 7) + k0 + lc * 8;
            unsigned dst = (unsigned)((i * 256 + (tid & ~63)) * 16);
            __builtin_amdgcn_global_load_lds(
                (const __attribute__((address_space(1))) void*)g,
                (__attribute__((address_space(3))) void*)((char*)Bs + dst), 16, 0, 0);
        }
    };

    f32x4 acc[4][4];
    #pragma unroll
    for (int i = 0; i < 4; ++i)
        #pragma unroll
        for (int j = 0; j < 4; ++j) acc[i][j] = (f32x4){0.f, 0.f, 0.f, 0.f};

    stage(0);
    __syncthreads();

    #pragma unroll
    for (int t = 0; t < 4; ++t) {
        short8_t aF[4], bF[4];
        const int kg = lane >> 4;
        #pragma unroll
        for (int mt = 0; mt < 4; ++mt) {
            int row = wr * 64 + mt * 16 + (lane & 15);
            int pc  = kg ^ swz(row);
            aF[mt] = *reinterpret_cast<const short8_t*>(As + row * 32 + pc * 8);
        }
        #pragma unroll
        for (int nt = 0; nt < 4; ++nt) {
            int row = wc * 64 + nt * 16 + (lane & 15);
            int pc  = kg ^ swz(row);
            bF[nt] = *reinterpret_cast<const short8_t*>(Bs + row * 32 + pc * 8);
        }
        #pragma unroll
        for (int mt = 0; mt < 4; ++mt)
            #pragma unroll
            for (int nt = 0; nt < 4; ++nt)
                acc[mt][nt] = __builtin_amdgcn_mfma_f32_16x16x32_bf16(
                    aF[mt], bF[nt], acc[mt][nt], 0, 0, 0);

        if (t < 3) {
            __syncthreads();
            stage((t + 1) * 32);
            __syncthreads();
        }
    }

    __syncthreads();   // staging dead; repurpose LDS as C tile

    #pragma unroll
    for (int nt = 0; nt < 4; ++nt) {
        int nl = wc * 64 + nt * 16 + (lane & 15);
        float cj = cvec[(size_t)l * N_ + bn0 + nl];
        #pragma unroll
        for (int mt = 0; mt < 4; ++mt) {
            #pragma unroll
            for (int j = 0; j < 4; ++j) {
                int rl = wr * 64 + mt * 16 + (lane >> 4) * 4 + j;
                smem[rl * CP + nl] = f2bf(acc[mt][nt][j] - cj);
            }
        }
    }
    __syncthreads();

    #pragma unroll
    for (int i = 0; i < 8; ++i) {
        int chunk = i * 256 + tid;
        int r = chunk >> 4, cch = chunk & 15;
        ushort8_t v = *reinterpret_cast<const ushort8_t*>(smem + r * CP + cch * 8);
        unsigned short* dst = y16 + ((size_t)((bm0 + r) * L_ + l)) * 8192 + 4096 + bn0 + cch * 8;
        *reinterpret_cast<ushort8_t*>(dst) = v;
    }
}

// ---------------------------------------------------------------------------
// K2 (wave-per-row selector+decoder, zero block barriers) == round 14 with
// the LDS-atomic pool replaced by a BALLOT/SCAN compaction: per-lane count,
// 6-step shfl_up inclusive scan, plain ds_writes at base+k. No atomics, one
// lgkmcnt drain instead of three, deterministic lane-major pool order.
// ---------------------------------------------------------------------------
#define POOL 96
#define MARGIN 1.2e-3f

__global__ __launch_bounds__(256) void topk_decode(float* __restrict__ y,
                                                   const float* __restrict__ We,
                                                   const float* __restrict__ WdT,
                                                   const float* __restrict__ kin,
                                                   const float* __restrict__ cvec,
                                                   int* __restrict__ cidx,
                                                   float* __restrict__ cval,
                                                   float* __restrict__ khat,
                                                   float* __restrict__ partial) {
    const int w    = threadIdx.x >> 6;          // wave id in block (0..3)
    const int lane = threadIdx.x & 63;
    const int wid  = (blockIdx.x << 2) + w;     // 0..32767, l-major
    const int l = wid >> 10, b = wid & 1023;
    const int row = b * L_ + l;

    __shared__ __align__(16) float kinS[4][M_];
    __shared__ int   pidxS[4][POOL];
    __shared__ float pexS[4][POOL];
    __shared__ int   sidxS[4][S_];
    __shared__ float svalS[4][S_];

    float* yo = y + (size_t)row * N_;
    const unsigned short* ya = (const unsigned short*)y + (size_t)row * 8192 + 4096;

    kinS[w][lane]      = kin[(size_t)row * M_ + lane];
    kinS[w][lane + 64] = kin[(size_t)row * M_ + lane + 64];

    // load 64 approx values (8 x 16B, coalesced)
    ushort8_t u[8];
    #pragma unroll
    for (int j = 0; j < 8; ++j)
        u[j] = *reinterpret_cast<const ushort8_t*>(ya + j * 512 + lane * 8);
    float a[64];
    #pragma unroll
    for (int j = 0; j < 8; ++j)
        #pragma unroll
        for (int e = 0; e < 8; ++e)
            a[j * 8 + e] = fabsf(bf2f(u[j][e]));

    // wave max + moments (for bisect seeding)
    float mx = 0.0f, s1 = 0.0f, s2 = 0.0f;
    #pragma unroll
    for (int i = 0; i < 64; ++i) {
        mx = fmaxf(mx, a[i]);
        s1 += a[i];
        s2 = fmaf(a[i], a[i], s2);
    }
    #pragma unroll
    for (int o = 32; o > 0; o >>= 1) {
        mx = fmaxf(mx, __shfl_xor(mx, o, 64));
        s1 += __shfl_xor(s1, o, 64);
        s2 += __shfl_xor(s2, o, 64);
    }
    const float mu  = s1 * (1.0f / 4096.0f);
    const float var = fmaxf(s2 * (1.0f / 4096.0f) - mu * mu, 0.0f);
    const float sg  = sqrtf(var);

    // bisect: invariant count(a >= lo) >= 32; tighten until count <= 40.
    // Iters 0/1 use folded-normal quantile seeds; wrong seeds only cost
    // iterations (invariant update unchanged), never correctness.
    float lo = 0.0f, hi = mx;
    int cl = N_;
    for (int it = 0; it < 30 && cl > 40; ++it) {
        float t;
        if      (it == 0) t = mu + 2.20f * sg;
        else if (it == 1) t = mu + 2.96f * sg;
        else              t = 0.5f * (lo + hi);
        t = fminf(fmaxf(t, lo), hi);
        int c = 0;
        #pragma unroll
        for (int i = 0; i < 64; ++i) c += (a[i] >= t) ? 1 : 0;
        #pragma unroll
        for (int o = 32; o > 0; o >>= 1) c += __shfl_xor(c, o, 64);
        if (c >= S_) { lo = t; cl = c; } else { hi = t; }
    }

    // pool via ballot/scan compaction (no atomics): per-lane count, 6-step
    // shfl_up inclusive scan, each lane writes its candidates at base+k.
    const float th = lo - MARGIN;
    int myc = 0;
    #pragma unroll
    for (int i = 0; i < 64; ++i) myc += (a[i] >= th) ? 1 : 0;
    int pos = myc;
    #pragma unroll
    for (int o = 1; o < 64; o <<= 1) {
        int t = __shfl_up(pos, o, 64);
        if (lane >= o) pos += t;
    }
    const int base  = pos - myc;                // exclusive prefix
    const int total = __shfl(pos, 63, 64);
    int k = 0;
    #pragma unroll
    for (int j = 0; j < 8; ++j)
        #pragma unroll
        for (int e = 0; e < 8; ++e)
            if (a[j * 8 + e] >= th) {
                int p = base + k;
                if (p < POOL) pidxS[w][p] = j * 512 + lane * 8 + e;
                ++k;
            }
    __asm__ __volatile__("s_waitcnt lgkmcnt(0)" ::: "memory");
    int c = total < POOL ? total : POOL;

    // exact recompute: STRICT ascending-m fmaf chain (bit-identical to r4);
    // float4 loads (We global L2-hot, kin LDS) then 4 in-order scalar fmafs.
    if (lane < c) {
        int n = pidxS[w][lane];
        const float4* wp4 = reinterpret_cast<const float4*>(We + ((size_t)l * N_ + n) * M_);
        const float4* kp4 = reinterpret_cast<const float4*>(kinS[w]);
        float acc = -cvec[(size_t)l * N_ + n];
        #pragma unroll 8
        for (int m4 = 0; m4 < 32; ++m4) {
            float4 wv = wp4[m4], kv = kp4[m4];
            acc = fmaf(wv.x, kv.x, acc);
            acc = fmaf(wv.y, kv.y, acc);
            acc = fmaf(wv.z, kv.z, acc);
            acc = fmaf(wv.w, kv.w, acc);
        }
        pexS[w][lane] = acc;
    }
    if (lane + 64 < c) {
        int n = pidxS[w][lane + 64];
        const float4* wp4 = reinterpret_cast<const float4*>(We + ((size_t)l * N_ + n) * M_);
        const float4* kp4 = reinterpret_cast<const float4*>(kinS[w]);
        float acc = -cvec[(size_t)l * N_ + n];
        #pragma unroll 8
        for (int m4 = 0; m4 < 32; ++m4) {
            float4 wv = wp4[m4], kv = kp4[m4];
            acc = fmaf(wv.x, kv.x, acc);
            acc = fmaf(wv.y, kv.y, acc);
            acc = fmaf(wv.z, kv.z, acc);
            acc = fmaf(wv.w, kv.w, acc);
        }
        pexS[w][lane + 64] = acc;
    }
    __asm__ __volatile__("s_waitcnt lgkmcnt(0)" ::: "memory");

    // exact rank (lowest-index tie-break); winners into LDS lists
    for (int e = lane; e < c; e += 64) {
        float ae = fabsf(pexS[w][e]);
        int   ne = pidxS[w][e];
        int rank = 0;
        for (int j = 0; j < c; ++j) {
            float aj = fabsf(pexS[w][j]);
            rank += ((aj > ae) || (aj == ae && pidxS[w][j] < ne)) ? 1 : 0;
        }
        if (rank < S_) {
            sidxS[w][rank] = ne;
            svalS[w][rank] = pexS[w][e];
        }
    }
    __asm__ __volatile__("s_waitcnt lgkmcnt(0)" ::: "memory");

    // emit winner lists; DIRECT scatter of low-half winners (that region was
    // zeroed by zero_y_low before the encoder and has no other writer)
    if (lane < S_) {
        int n = sidxS[w][lane];
        float v = svalS[w][lane];
        cidx[(size_t)row * S_ + lane] = n;
        cval[(size_t)row * S_ + lane] = v;
        if (n < 2048) yo[n] = v;
    }

    // fused decode: 2 dims per lane; WdT rows L2-resident (l-major)
    const float* wt = WdT + (size_t)l * N_ * M_;
    float acc0 = 0.0f, acc1 = 0.0f;
    #pragma unroll 4
    for (int j = 0; j < S_; ++j) {
        float v = svalS[w][j];
        const float* wrp = wt + (size_t)sidxS[w][j] * M_;
        acc0 = fmaf(v, wrp[lane], acc0);
        acc1 = fmaf(v, wrp[lane + 64], acc1);
    }
    khat[(size_t)row * M_ + lane]      = acc0;
    khat[(size_t)row * M_ + lane + 64] = acc1;
    float r0 = acc0 - kinS[w][lane];
    float r1 = acc1 - kinS[w][lane + 64];
    float s = r0 * r0 + r1 * r1;
    #pragma unroll
    for (int o = 32; o > 0; o >>= 1) s += __shfl_xor(s, o, 64);
    if (lane == 0) partial[row] = s;
}

// ---------------------------------------------------------------------------
// K4: deterministic reduction of 32768 partials -> loss (float4 loads)
// ---------------------------------------------------------------------------
__global__ __launch_bounds__(256) void reduce_loss(const float* __restrict__ partial,
                                                   float* __restrict__ out_loss) {
    __shared__ float red[256];
    int tid = threadIdx.x;
    float s = 0.0f;
    for (int i = tid; i < ROWS / 4; i += 256) {
        float4 v = reinterpret_cast<const float4*>(partial)[i];
        s += v.x + v.y + v.z + v.w;
    }
    red[tid] = s;
    __syncthreads();
    for (int off = 128; off > 0; off >>= 1) {
        if (tid < off) red[tid] += red[tid + off];
        __syncthreads();
    }
    if (tid == 0) out_loss[0] = red[0] / (float)((size_t)B_ * L_ * M_);
}

// ---------------------------------------------------------------------------
extern "C" void kernel_launch(void* const* d_in, const int* in_sizes, int n_in,
                              void* d_out, int out_size, void* d_ws, size_t ws_size,
                              hipStream_t stream) {
    const float* kin = (const float*)d_in[0];   // [B][L][M]
    const float* We  = (const float*)d_in[1];   // [L][N][M]
    // d_in[2] = b_e (unused by reference encode())
    const float* Wd  = (const float*)d_in[3];   // [L][M][N]
    const float* bd  = (const float*)d_in[4];   // [L][M]
    // d_in[5] = s (==32, hardcoded)

    float* out   = (float*)d_out;
    float* loss  = out;                                   // [1]
    float* khat  = out + 1;                               // [B*L*M]
    float* y_out = out + 1 + (size_t)B_ * L_ * M_;        // [B*L*N]

    // workspace layout (region0 shared: Wbf during encode, WdT after)
    char* ws = (char*)d_ws;
    unsigned short* Wbf = (unsigned short*)ws;                   // 32 MiB (in 64 MiB region0)
    float*          WdT = (float*)ws;                            // 64 MiB (aliases Wbf)
    unsigned short* Abf = (unsigned short*)(ws + (64u << 20));   // 8 MiB
    int*   cidx    = (int*)  (ws + (72u << 20));                 // 4 MiB
    float* cval    = (float*)(ws + (76u << 20));                 // 4 MiB
    float* cvec    = (float*)(ws + (80u << 20));                 // 512 KiB
    float* partial = (float*)(ws + (81u << 20));                 // 128 KiB

    // zero low halves of y first (approx lives in high halves)
    zero_y_low<<<2048, 256, 0, stream>>>(y_out);
    prep_w<<<dim3(N_ / 16, L_), 256, 0, stream>>>(We, bd, Wbf, cvec);
    prep_a<<<(B_ * L_ * M_) / 256, 256, 0, stream>>>(kin, Abf);
    encoder_mfma<<<dim3(N_ / 128, B_ / 128, L_), 256, 0, stream>>>(
        Abf, Wbf, cvec, (unsigned short*)y_out);
    // Wbf dead now; transpose overwrites region0 with WdT
    transpose_wd<<<dim3(N_ / 32, M_ / 32, L_), 256, 0, stream>>>(Wd, WdT);
    // wave-per-row selector + decoder (direct low-half scatter)
    topk_decode<<<ROWS / 4, 256, 0, stream>>>(y_out, We, WdT, kin, cvec,
                                              cidx, cval, khat, partial);
    // streaming finishers: zero high halves, then scatter high winners
    zero_y_high<<<2048, 256, 0, stream>>>(y_out);
    scatter_high<<<(ROWS * S_) / 256, 256, 0, stream>>>(y_out, cidx, cval);
    reduce_loss<<<1, 256, 0, stream>>>(partial, loss);
}